// Round 6
// baseline (4303.992 us; speedup 1.0000x reference)
//
#include <hip/hip_runtime.h>
#include <hip/hip_bf16.h>

// WeightedGNN forward, MI355X. Round 6: single persistent kernel for all 64
// recurrence steps. Key fact: the recurrence is independent per batch b ->
// only a per-b 4-block barrier is needed (atomic counter + device fences),
// no grid-wide sync, no per-iteration launches.
// 64 blocks x 1024 thr (4 blocks/b, b%8 == blockIdx%8 -> XCD-local traffic).
// B=16, L=64, D=256, NRELS=8.

#define DD 256
#define LLEN 64
#define BBAT 16
#define NROWS 1024   // B*L

typedef __attribute__((ext_vector_type(8))) short short8;   // 8 bf16 = 4 VGPRs
typedef __attribute__((ext_vector_type(4))) short short4v;  // 4 bf16 = 2 VGPRs
typedef __attribute__((ext_vector_type(4))) float f32x4;

__device__ inline unsigned short f2bf(float x) {
    unsigned int u = __float_as_uint(x);
    unsigned int r = (u + 0x7fffu + ((u >> 16) & 1u)) >> 16;
    return (unsigned short)r;
}

// per-b barrier: monotonic counter, nb arrivals per phase; device-scope fences
__device__ inline void b_bar(int* barp, int target, int t) {
    __syncthreads();
    if (t == 0) {
        __threadfence();   // release: drain this block's stores past L2 (cross-XCD)
        __hip_atomic_fetch_add(barp, 1, __ATOMIC_RELAXED, __HIP_MEMORY_SCOPE_AGENT);
        while (__hip_atomic_load(barp, __ATOMIC_RELAXED, __HIP_MEMORY_SCOPE_AGENT) < target)
            __builtin_amdgcn_s_sleep(2);
        __threadfence();   // acquire: invalidate stale lines
    }
    __syncthreads();
}

// ------- one-time: W_proj [256][2048] fp32 -> bf16 B-fragment layout ----------
__global__ __launch_bounds__(256) void k_cvtW(const float* __restrict__ Wp,
                                              unsigned short* __restrict__ Wf) {
    int t = blockIdx.x * 256 + threadIdx.x;   // 65536
    int l = t & 63; int rest = t >> 6;
    int tk = rest & 7; rest >>= 3;
    int tn = rest & 15; int hh = rest >> 4;
    int kbase = tk * 32 + (l >> 4) * 8;
    int n = hh * 256 + tn * 16 + (l & 15);
    union { short8 v; unsigned short u[8]; } pk;
#pragma unroll
    for (int j = 0; j < 8; ++j) pk.u[j] = f2bf(Wp[(kbase + j) * 2048 + n]);
    *(short8*)(Wf + (long)t * 8) = pk.v;
}

// ------- one-time: A_rels -> bf16 A-fragment layout, K-order k = h*64 + i -----
__global__ __launch_bounds__(256) void k_cvtA(const float* __restrict__ A,
                                              unsigned short* __restrict__ Af) {
    int t = blockIdx.x * 256 + threadIdx.x;   // 65536
    int lane = t & 63;
    int tk = (t >> 6) & 15;
    int jg = (t >> 10) & 3;
    int b  = t >> 12;
    int j = jg * 16 + (lane & 15);
    int kbase = tk * 32 + (lane >> 4) * 8;
    int h  = kbase >> 6;
    int i0 = kbase & 63;
    union { short8 v; unsigned short u[8]; } pk;
#pragma unroll
    for (int jj = 0; jj < 8; ++jj)
        pk.u[jj] = f2bf(A[((long)(b * 64 + i0 + jj) * 64 + j) * 8 + h]);
    *(short8*)(Af + (long)t * 8) = pk.v;
}

// ------- one-time: W_out [256][256] fp32 -> bf16 B-fragment layout ------------
__global__ __launch_bounds__(256) void k_cvtWo(const float* __restrict__ Wo,
                                               unsigned short* __restrict__ Wof) {
    int t = blockIdx.x * 256 + threadIdx.x;   // 8192
    int lane = t & 63;
    int tk = (t >> 6) & 7;
    int nt = t >> 9;
    int kbase = tk * 32 + (lane >> 4) * 8;
    int n = nt * 16 + (lane & 15);
    union { short8 v; unsigned short u[8]; } pk;
#pragma unroll
    for (int j = 0; j < 8; ++j) pk.u[j] = f2bf(Wo[(kbase + j) * 256 + n]);
    *(short8*)(Wof + (long)t * 8) = pk.v;
}

// ---------------- in_proj: gather emb + [1024x256]@[256x768] -----------------
__global__ __launch_bounds__(256) void k_inproj(
    const int* __restrict__ tokens, const float* __restrict__ emb,
    const float* __restrict__ W_in, const float* __restrict__ b_in,
    float* __restrict__ shiftb, float* __restrict__ scaleb, float* __restrict__ projx)
{
    __shared__ float xs[8][DD];
    const int t = threadIdx.x;
    const int row0 = blockIdx.x * 8;
    for (int r = 0; r < 8; ++r) {
        int row = row0 + r;
        int b = row >> 6, l = row & 63;
        int tok = tokens[l * BBAT + b];
        xs[r][t] = emb[(long)tok * DD + t];
    }
    __syncthreads();
    float a0[8], a1[8], a2[8];
#pragma unroll
    for (int r = 0; r < 8; ++r) { a0[r] = a1[r] = a2[r] = 0.f; }
    for (int k = 0; k < DD; ++k) {
        float w0 = W_in[k * 768 + t];
        float w1 = W_in[k * 768 + 256 + t];
        float w2 = W_in[k * 768 + 512 + t];
#pragma unroll
        for (int r = 0; r < 8; ++r) {
            float x = xs[r][k];
            a0[r] = fmaf(x, w0, a0[r]);
            a1[r] = fmaf(x, w1, a1[r]);
            a2[r] = fmaf(x, w2, a2[r]);
        }
    }
    float bi0 = b_in[t], bi1 = b_in[256 + t], bi2 = b_in[512 + t];
#pragma unroll
    for (int r = 0; r < 8; ++r) {
        int row = row0 + r;
        shiftb[row * DD + t] = a0[r] + bi0;
        scaleb[row * DD + t] = a1[r] + bi1;
        projx [row * DD + t] = a2[r] + bi2;
    }
}

// ---------------- persistent: all 64 iterations ------------------------------
// block (blk): b = (blk&7)+8*((blk>>3)&1)  [b%8 == blk%8 -> XCD affinity],
// s16 = blk>>4 in 0..3 = phase1 rowgroup (16 rows) = phase2 j-group.
// Phase1: 4 subs x 2 uu cover the 8 hh chunks for this rowgroup; in-fragment
// LN (shuffle over lane-bits 0..3 + 4-wave partials) + fragment-layout stores.
// Phase2: R5 k_agg structure verbatim (16 waves, nt=w, 16 preloaded B-frags).
__global__ __launch_bounds__(1024) void k_fused(
    const int* __restrict__ tokens,
    const unsigned short* __restrict__ Af,     // [16][4][16][64][8]
    const unsigned short* __restrict__ Wf,     // [8*16][8][64][8]
    const unsigned short* __restrict__ Wof,    // [16][8][64][8]
    const float* __restrict__ bp,
    const float* __restrict__ bout,
    const float* __restrict__ projx,
    const float* __restrict__ shiftb,
    const float* __restrict__ scaleb,
    const float* __restrict__ root,
    unsigned short* __restrict__ h_bf,         // [1024][256] bf16 (zeroed)
    unsigned short* __restrict__ Pf,           // [16][16][16][64][8] bf16
    float* __restrict__ h_out,                 // [1024][256] fp32 (last iter)
    float* __restrict__ out,                   // [16][256]
    int* __restrict__ bars)                    // [16][32] zeroed
{
    __shared__ float p1part[4][2][4][16][2];   // [sub][uu][wv][row][sum,sumsq]
    __shared__ float Cs2[16][260];
    __shared__ unsigned short hsb[16][264];
    __shared__ float part2[16][4][2];
    __shared__ int len_s;

    const int t = threadIdx.x;
    const int lane = t & 63;
    const int q = lane >> 4;
    const int blk = blockIdx.x;
    const int b = (blk & 7) + 8 * ((blk >> 3) & 1);
    const int s16 = blk >> 4;                  // 0..3
    const int sub = t >> 8;                    // phase1 sub-block (256 thr)
    const int wv = (t >> 6) & 3;               // wave within sub
    const int w = t >> 6;                      // wave within block (phase2)

    if (t < 64) {
        int tok = tokens[t * BBAT + b];
        unsigned long long m = __ballot(tok != 0);
        if (t == 0) len_s = __popcll(m);
    }
    __syncthreads();

    int* barp = bars + b * 32;
    int barcnt = 0;
    const int row0 = b * 64 + s16 * 16;
    const int j0 = s16 * 16;

    for (int it = 0; it < 64; ++it) {
        // =================== phase 1: Pf = LN(h @ Wp + bp) ===================
#pragma unroll
        for (int uu = 0; uu < 2; ++uu) {
            const int hh = sub * 2 + uu;
            f32x4 acc[4];
#pragma unroll
            for (int tn = 0; tn < 4; ++tn) acc[tn] = (f32x4){0.f, 0.f, 0.f, 0.f};
            const unsigned short* aRow = h_bf + (row0 + (lane & 15)) * DD + q * 8;
            const unsigned short* wBase = Wf + ((long)(hh * 16 + wv * 4) * 8) * 512 + lane * 8;
            short8 a8[8];
#pragma unroll
            for (int tk = 0; tk < 8; ++tk) a8[tk] = *(const short8*)(aRow + tk * 32);
#pragma unroll
            for (int tk = 0; tk < 8; ++tk) {
#pragma unroll
                for (int tn = 0; tn < 4; ++tn) {
                    short8 bb = *(const short8*)(wBase + (long)(tn * 8 + tk) * 512);
                    acc[tn] = __builtin_amdgcn_mfma_f32_16x16x32_bf16(a8[tk], bb, acc[tn], 0, 0, 0);
                }
            }
            // rows m=q*4+r, cols d=wv*64+tn*16+(lane&15); LN over d (256 cols)
            float bpv[4];
#pragma unroll
            for (int tn = 0; tn < 4; ++tn)
                bpv[tn] = bp[hh * 256 + wv * 64 + tn * 16 + (lane & 15)];
            float v[4][4], s[4], ss[4];
#pragma unroll
            for (int r = 0; r < 4; ++r) {
                s[r] = 0.f; ss[r] = 0.f;
#pragma unroll
                for (int tn = 0; tn < 4; ++tn) {
                    float x = acc[tn][r] + bpv[tn];
                    v[tn][r] = x;
                    s[r] += x; ss[r] += x * x;
                }
#pragma unroll
                for (int msk = 1; msk < 16; msk <<= 1) {
                    s[r]  += __shfl_xor(s[r],  msk);
                    ss[r] += __shfl_xor(ss[r], msk);
                }
            }
            if ((lane & 15) == 0) {
#pragma unroll
                for (int r = 0; r < 4; ++r) {
                    p1part[sub][uu][wv][q * 4 + r][0] = s[r];
                    p1part[sub][uu][wv][q * 4 + r][1] = ss[r];
                }
            }
            __syncthreads();
            float mean[4], rstd[4];
#pragma unroll
            for (int r = 0; r < 4; ++r) {
                int mrow = q * 4 + r;
                float S  = p1part[sub][uu][0][mrow][0] + p1part[sub][uu][1][mrow][0]
                         + p1part[sub][uu][2][mrow][0] + p1part[sub][uu][3][mrow][0];
                float SS = p1part[sub][uu][0][mrow][1] + p1part[sub][uu][1][mrow][1]
                         + p1part[sub][uu][2][mrow][1] + p1part[sub][uu][3][mrow][1];
                float mn = S * (1.f / 256.f);
                float var = SS * (1.f / 256.f) - mn * mn;
                mean[r] = mn;
                rstd[r] = rsqrtf(var + 1e-5f);
            }
            // store in B-fragment layout: k = hh*64 + i, i = s16*16 + q*4 + r
            const int kbase = hh * 64 + s16 * 16 + q * 4;
            const int tk1 = kbase >> 5;
            const int rowsel = (kbase >> 3) & 3;
            const int jlo = (q & 1) * 4;      // jlo + r == k & 7
#pragma unroll
            for (int tn = 0; tn < 4; ++tn) {
                short4v pk;
#pragma unroll
                for (int r = 0; r < 4; ++r)
                    pk[r] = (short)f2bf((v[tn][r] - mean[r]) * rstd[r]);
                long off = (long)b * 131072 + (long)tk1 * 8192 + (wv * 4 + tn) * 512
                         + (rowsel * 16 + (lane & 15)) * 8 + jlo;
                *(short4v*)(Pf + off) = pk;
            }
        }
        ++barcnt; b_bar(barp, barcnt * 4, t);   // Pf[b] complete across 4 blocks

        // =================== phase 2: agg + gate + Wout ======================
        {
            const unsigned short* ab = Af + ((long)(b * 4 + s16) * 16) * 512 + lane * 8;
            const unsigned short* pb = Pf + (long)b * 131072 + w * 512 + lane * 8;
            short8 bfr[16];
#pragma unroll
            for (int tk = 0; tk < 16; ++tk) bfr[tk] = *(const short8*)(pb + (long)tk * 8192);
            f32x4 acg = (f32x4){0.f, 0.f, 0.f, 0.f};
#pragma unroll
            for (int tk = 0; tk < 16; ++tk) {
                short8 a = *(const short8*)(ab + (long)tk * 512);
                acg = __builtin_amdgcn_mfma_f32_16x16x32_bf16(a, bfr[tk], acg, 0, 0, 0);
            }
            {
                int n = w * 16 + (lane & 15);
                int m0 = q * 4;
#pragma unroll
                for (int r = 0; r < 4; ++r) Cs2[m0 + r][n] = acg[r];
            }
            __syncthreads();
            const int d = t & 255;
            const int rbase = (w >> 2) * 4;
            const int dseg = w & 3;
            float tv[4];
#pragma unroll
            for (int ri = 0; ri < 4; ++ri) {
                int row = b * 64 + j0 + rbase + ri;
                float lin = Cs2[rbase + ri][d];
                float shr = lin - tanhf(lin);
                tv[ri] = projx[row * DD + d] + shr;
            }
#pragma unroll
            for (int ri = 0; ri < 4; ++ri) {
                float sv = tv[ri], sq = tv[ri] * tv[ri];
#pragma unroll
                for (int msk = 32; msk >= 1; msk >>= 1) {
                    sv += __shfl_xor(sv, msk);
                    sq += __shfl_xor(sq, msk);
                }
                if (lane == 0) { part2[rbase + ri][dseg][0] = sv; part2[rbase + ri][dseg][1] = sq; }
            }
            __syncthreads();
#pragma unroll
            for (int ri = 0; ri < 4; ++ri) {
                int r = rbase + ri;
                int row = b * 64 + j0 + r;
                float S  = part2[r][0][0] + part2[r][1][0] + part2[r][2][0] + part2[r][3][0];
                float SS = part2[r][0][1] + part2[r][1][1] + part2[r][2][1] + part2[r][3][1];
                float mn = S * (1.f / 256.f);
                float var = SS * (1.f / 256.f) - mn * mn;
                float rs = rsqrtf(var + 1e-5f);
                float nv = (tv[ri] - mn) * rs;
                float hv = fmaf(shiftb[row * DD + d], nv, scaleb[row * DD + d]);
                hsb[r][d] = f2bf(fmaxf(hv, 0.f));
            }
            __syncthreads();
            f32x4 ac2 = (f32x4){0.f, 0.f, 0.f, 0.f};
#pragma unroll
            for (int tk = 0; tk < 8; ++tk) {
                short8 a = *(const short8*)(&hsb[lane & 15][tk * 32 + q * 8]);
                short8 wf = *(const short8*)(Wof + (long)(w * 8 + tk) * 512 + lane * 8);
                ac2 = __builtin_amdgcn_mfma_f32_16x16x32_bf16(a, wf, ac2, 0, 0, 0);
            }
            {
                int n = w * 16 + (lane & 15);
                int m0 = q * 4;
#pragma unroll
                for (int r = 0; r < 4; ++r) Cs2[m0 + r][n] = ac2[r];
            }
            __syncthreads();
            const float bo_d = bout[d];
            const bool maskz = ((64 - it) > len_s);
#pragma unroll
            for (int ri = 0; ri < 4; ++ri) {
                int r = rbase + ri;
                int row = b * 64 + j0 + r;
                float y = tanhf(Cs2[r][d] + bo_d);
                float ym = maskz ? 0.f : y;
                h_bf[row * DD + d] = f2bf(ym);
                if (it == 63) h_out[row * DD + d] = ym;
            }
        }
        ++barcnt; b_bar(barp, barcnt * 4, t);   // h(b) complete across 4 blocks
    }

    // ---------------- final: out[b,d] = sum_i h[b,i,d] * root[b,i] -----------
    if (s16 == 0 && t < 256) {
        float accf = 0.f;
        for (int i2 = 0; i2 < 64; ++i2)
            accf = fmaf(h_out[(b * 64 + i2) * DD + t], root[b * 64 + i2], accf);
        out[b * DD + t] = accf;
    }
}

extern "C" void kernel_launch(void* const* d_in, const int* in_sizes, int n_in,
                              void* d_out, int out_size, void* d_ws, size_t ws_size,
                              hipStream_t stream)
{
    const int*   tokens = (const int*)  d_in[0];
    const float* A      = (const float*)d_in[1];
    const float* root   = (const float*)d_in[2];
    const float* emb    = (const float*)d_in[3];
    const float* Wp     = (const float*)d_in[4];
    const float* bp     = (const float*)d_in[5];
    const float* Wi     = (const float*)d_in[6];
    const float* bi     = (const float*)d_in[7];
    const float* Wo     = (const float*)d_in[8];
    const float* bo     = (const float*)d_in[9];
    float* out = (float*)d_out;

    char* ws = (char*)d_ws;
    int*   bars    = (int*)(ws + 0);                            // 2 KB (pad 4 KB)
    float* shiftb  = (float*)(ws + 4096);
    float* scaleb  = shiftb + NROWS * DD;
    float* projx   = scaleb + NROWS * DD;
    float* h_out   = projx  + NROWS * DD;                       // 1 MB fp32
    unsigned short* h_bf = (unsigned short*)(h_out + NROWS * DD);  // 512 KB
    unsigned short* Wf   = h_bf + NROWS * DD;                   // 1 MB
    unsigned short* Pf   = Wf + 524288;                         // 4 MB
    unsigned short* Af   = Pf + 2097152;                        // 1 MB
    unsigned short* Wof  = Af + 524288;                         // 128 KB

    hipMemsetAsync(bars, 0, 4096, stream);
    hipMemsetAsync(h_bf, 0, (size_t)NROWS * DD * sizeof(unsigned short), stream);
    k_cvtW<<<256, 256, 0, stream>>>(Wp, Wf);
    k_cvtA<<<256, 256, 0, stream>>>(A, Af);
    k_cvtWo<<<32, 256, 0, stream>>>(Wo, Wof);
    k_inproj<<<128, 256, 0, stream>>>(tokens, emb, Wi, bi, shiftb, scaleb, projx);
    k_fused<<<64, 1024, 0, stream>>>(tokens, Af, Wf, Wof, bp, bo, projx, shiftb, scaleb,
                                     root, h_bf, Pf, h_out, out, bars);
}

// Round 8
// 3181.234 us; speedup vs baseline: 1.3529x; 1.3529x over previous
//
#include <hip/hip_runtime.h>
#include <hip/hip_bf16.h>

// WeightedGNN forward, MI355X. Round 8: R7 persistent design with two fixes:
// (1) LDS overlaid in a union -> 33.8 KB < 64 KB per-workgroup cap (R7's 68.6 KB
//     silently failed to launch -> all-zero output);
// (2) h-staging addressing fixed (R7 read wrong stride / half the bytes).
// Cross-block data (Pf, h_bf) via relaxed agent-scope atomic u64 (coherent at
// L3, no cache invalidation); read-only data stays in normal cached loads.
// 64 blocks x 1024 thr; block (b=blk&15 mapped, s16=blk>>4). Per-b barriers.
// B=16, L=64, D=256, NRELS=8.

#define DD 256
#define LLEN 64
#define BBAT 16
#define NROWS 1024   // B*L

typedef __attribute__((ext_vector_type(8))) short short8;   // 8 bf16 = 4 VGPRs
typedef __attribute__((ext_vector_type(4))) float f32x4;

__device__ inline unsigned short f2bf(float x) {
    unsigned int u = __float_as_uint(x);
    unsigned int r = (u + 0x7fffu + ((u >> 16) & 1u)) >> 16;
    return (unsigned short)r;
}

__device__ inline void st64(unsigned long long* p, unsigned long long v) {
    __hip_atomic_store(p, v, __ATOMIC_RELAXED, __HIP_MEMORY_SCOPE_AGENT);
}
__device__ inline unsigned long long ld64(const unsigned long long* p) {
    return __hip_atomic_load(p, __ATOMIC_RELAXED, __HIP_MEMORY_SCOPE_AGENT);
}

// per-b barrier: no fences (no L2 invalidation). Own stores drained per-thread
// (s_waitcnt 0) before arrival; shared data moves via sc-coherent atomics only.
__device__ inline void bar_b(int* barp, int target, int t) {
    __builtin_amdgcn_s_waitcnt(0);
    __syncthreads();
    if (t == 0) {
        __hip_atomic_fetch_add(barp, 1, __ATOMIC_RELAXED, __HIP_MEMORY_SCOPE_AGENT);
        while (__hip_atomic_load(barp, __ATOMIC_RELAXED, __HIP_MEMORY_SCOPE_AGENT) < target)
            __builtin_amdgcn_s_sleep(2);
    }
    __syncthreads();
}

// ------- one-time: W_proj [256][2048] fp32 -> bf16 B-fragment layout ----------
__global__ __launch_bounds__(256) void k_cvtW(const float* __restrict__ Wp,
                                              unsigned short* __restrict__ Wf) {
    int t = blockIdx.x * 256 + threadIdx.x;   // 65536
    int l = t & 63; int rest = t >> 6;
    int tk = rest & 7; rest >>= 3;
    int tn = rest & 15; int hh = rest >> 4;
    int kbase = tk * 32 + (l >> 4) * 8;
    int n = hh * 256 + tn * 16 + (l & 15);
    union { short8 v; unsigned short u[8]; } pk;
#pragma unroll
    for (int j = 0; j < 8; ++j) pk.u[j] = f2bf(Wp[(kbase + j) * 2048 + n]);
    *(short8*)(Wf + (long)t * 8) = pk.v;
}

// ------- one-time: A_rels -> bf16 A-fragment layout, K-order k = h*64 + i -----
__global__ __launch_bounds__(256) void k_cvtA(const float* __restrict__ A,
                                              unsigned short* __restrict__ Af) {
    int t = blockIdx.x * 256 + threadIdx.x;   // 65536
    int lane = t & 63;
    int tk = (t >> 6) & 15;
    int jg = (t >> 10) & 3;
    int b  = t >> 12;
    int j = jg * 16 + (lane & 15);
    int kbase = tk * 32 + (lane >> 4) * 8;
    int h  = kbase >> 6;
    int i0 = kbase & 63;
    union { short8 v; unsigned short u[8]; } pk;
#pragma unroll
    for (int jj = 0; jj < 8; ++jj)
        pk.u[jj] = f2bf(A[((long)(b * 64 + i0 + jj) * 64 + j) * 8 + h]);
    *(short8*)(Af + (long)t * 8) = pk.v;
}

// ------- one-time: W_out [256][256] fp32 -> bf16 B-fragment layout ------------
__global__ __launch_bounds__(256) void k_cvtWo(const float* __restrict__ Wo,
                                               unsigned short* __restrict__ Wof) {
    int t = blockIdx.x * 256 + threadIdx.x;   // 8192
    int lane = t & 63;
    int tk = (t >> 6) & 7;
    int nt = t >> 9;
    int kbase = tk * 32 + (lane >> 4) * 8;
    int n = nt * 16 + (lane & 15);
    union { short8 v; unsigned short u[8]; } pk;
#pragma unroll
    for (int j = 0; j < 8; ++j) pk.u[j] = f2bf(Wo[(kbase + j) * 256 + n]);
    *(short8*)(Wof + (long)t * 8) = pk.v;
}

// ---------------- in_proj: gather emb + [1024x256]@[256x768] -----------------
__global__ __launch_bounds__(256) void k_inproj(
    const int* __restrict__ tokens, const float* __restrict__ emb,
    const float* __restrict__ W_in, const float* __restrict__ b_in,
    float* __restrict__ shiftb, float* __restrict__ scaleb, float* __restrict__ projx)
{
    __shared__ float xs[8][DD];
    const int t = threadIdx.x;
    const int row0 = blockIdx.x * 8;
    for (int r = 0; r < 8; ++r) {
        int row = row0 + r;
        int b = row >> 6, l = row & 63;
        int tok = tokens[l * BBAT + b];
        xs[r][t] = emb[(long)tok * DD + t];
    }
    __syncthreads();
    float a0[8], a1[8], a2[8];
#pragma unroll
    for (int r = 0; r < 8; ++r) { a0[r] = a1[r] = a2[r] = 0.f; }
    for (int k = 0; k < DD; ++k) {
        float w0 = W_in[k * 768 + t];
        float w1 = W_in[k * 768 + 256 + t];
        float w2 = W_in[k * 768 + 512 + t];
#pragma unroll
        for (int r = 0; r < 8; ++r) {
            float x = xs[r][k];
            a0[r] = fmaf(x, w0, a0[r]);
            a1[r] = fmaf(x, w1, a1[r]);
            a2[r] = fmaf(x, w2, a2[r]);
        }
    }
    float bi0 = b_in[t], bi1 = b_in[256 + t], bi2 = b_in[512 + t];
#pragma unroll
    for (int r = 0; r < 8; ++r) {
        int row = row0 + r;
        shiftb[row * DD + t] = a0[r] + bi0;
        scaleb[row * DD + t] = a1[r] + bi1;
        projx [row * DD + t] = a2[r] + bi2;
    }
}

// ---------------- persistent: all 64 iterations ------------------------------
__global__ __launch_bounds__(1024) void k_fused(
    const int* __restrict__ tokens,
    const unsigned short* __restrict__ Af,     // [16][4][16][64][8]
    const unsigned short* __restrict__ Wf,     // [8*16][8][64][8]
    const unsigned short* __restrict__ Wof,    // [16][8][64][8]
    const float* __restrict__ bp,
    const float* __restrict__ bout,
    const float* __restrict__ projx,
    const float* __restrict__ shiftb,
    const float* __restrict__ scaleb,
    const float* __restrict__ root,
    unsigned long long* __restrict__ h_bf64,   // [1024][256] bf16 as u64 (zeroed)
    unsigned long long* __restrict__ Pf64,     // [16][16][16][64][8] bf16 as u64
    float* __restrict__ out,                   // [16][256] (zeroed)
    int* __restrict__ bars)                    // zeroed
{
    // Overlaid LDS: phases are temporally disjoint (barriers between) -> 33.8 KB
    __shared__ union __align__(16) {
        unsigned short hpb[64][264];                       // 33792 B  (phase-1 staging)
        struct { float p1part[2][64][8][2];                //  8192 B  (phase-1 LN)
                 float mstat[2][64][2]; } p1;              //  1024 B
        struct { float Cs2[16][260];                       // 16640 B  (phase-2)
                 unsigned short hsb[16][264];              //  8448 B
                 float part2[16][4][2]; } p2;              //   512 B
    } sm;
    __shared__ int len_s;

    const int t = threadIdx.x;
    const int w = t >> 6;                      // wave 0..15
    const int lane = t & 63;
    const int q = lane >> 4;                   // 0..3
    const int ln = lane & 15;
    const int blk = blockIdx.x;
    const int b = (blk & 7) + 8 * ((blk >> 3) & 1);   // b%8 == blk%8 (XCD affinity)
    const int s16 = blk >> 4;                  // 0..3
    const int j0 = s16 * 16;
    const int hh_l = w >> 3;                   // phase1: which of my 2 hh
    const int np = w & 7;                      // phase1: ntile-pair 0..7
    const int hh = s16 * 2 + hh_l;

    if (t < 64) {
        int tok = tokens[t * BBAT + b];
        unsigned long long m = __ballot(tok != 0);
        if (t == 0) len_s = __popcll(m);
    }
    __syncthreads();

    int* barp = bars + b * 32;
    int barcnt = 0;

    for (int it = 0; it < 64; ++it) {
        // ---- stage h(b): 32 KB, sc-coherent u64 loads -> LDS ----
        {
            const unsigned long long* srcb = h_bf64 + (long)b * 4096;
#pragma unroll
            for (int e = t; e < 2048; e += 1024) {
                int row = e >> 5, cq = e & 31;
                union { unsigned long long q2[2]; short8 v; } u;
                u.q2[0] = ld64(srcb + row * 64 + cq * 2);
                u.q2[1] = ld64(srcb + row * 64 + cq * 2 + 1);
                *(short8*)(&sm.hpb[row][cq * 8]) = u.v;
            }
        }
        __syncthreads();

        // ======== phase 1: Pf = LN(h @ Wp + bp), my 2 hh, all 64 rows ========
        {
            f32x4 acc[2][4];
#pragma unroll
            for (int nl = 0; nl < 2; ++nl)
#pragma unroll
                for (int rt = 0; rt < 4; ++rt) acc[nl][rt] = (f32x4){0.f, 0.f, 0.f, 0.f};
#pragma unroll
            for (int tk = 0; tk < 8; ++tk) {
                short8 a[4];
#pragma unroll
                for (int rt = 0; rt < 4; ++rt)
                    a[rt] = *(const short8*)(&sm.hpb[rt * 16 + ln][tk * 32 + q * 8]);
#pragma unroll
                for (int nl = 0; nl < 2; ++nl) {
                    int nt = np * 2 + nl;
                    short8 bb = *(const short8*)(Wf + ((long)(hh * 16 + nt) * 8 + tk) * 512 + lane * 8);
#pragma unroll
                    for (int rt = 0; rt < 4; ++rt)
                        acc[nl][rt] = __builtin_amdgcn_mfma_f32_16x16x32_bf16(a[rt], bb, acc[nl][rt], 0, 0, 0);
                }
            }
            __syncthreads();   // hpb reads done -> safe to overwrite (p1part alias)

            float bpv[2];
#pragma unroll
            for (int nl = 0; nl < 2; ++nl) bpv[nl] = bp[hh * 256 + (np * 2 + nl) * 16 + ln];
#pragma unroll
            for (int rt = 0; rt < 4; ++rt) {
#pragma unroll
                for (int r = 0; r < 4; ++r) {
                    float x0 = acc[0][rt][r] + bpv[0];
                    float x1 = acc[1][rt][r] + bpv[1];
                    acc[0][rt][r] = x0; acc[1][rt][r] = x1;
                    float s = x0 + x1, ss = x0 * x0 + x1 * x1;
#pragma unroll
                    for (int msk = 1; msk < 16; msk <<= 1) {
                        s += __shfl_xor(s, msk); ss += __shfl_xor(ss, msk);
                    }
                    if (ln == 0) {
                        sm.p1.p1part[hh_l][rt * 16 + q * 4 + r][np][0] = s;
                        sm.p1.p1part[hh_l][rt * 16 + q * 4 + r][np][1] = ss;
                    }
                }
            }
            __syncthreads();
            if (t < 128) {
                int hl = t >> 6, m = t & 63;
                float S = 0.f, SS = 0.f;
#pragma unroll
                for (int p = 0; p < 8; ++p) { S += sm.p1.p1part[hl][m][p][0]; SS += sm.p1.p1part[hl][m][p][1]; }
                float mean = S * (1.f / 256.f);
                float var = SS * (1.f / 256.f) - mean * mean;
                sm.p1.mstat[hl][m][0] = mean;
                sm.p1.mstat[hl][m][1] = rsqrtf(var + 1e-5f);
            }
            __syncthreads();
            // store to Pf (B-frag layout, k = hh*64+i) via sc-coherent u64
#pragma unroll
            for (int rt = 0; rt < 4; ++rt) {
                float mn[4], rs[4];
#pragma unroll
                for (int r = 0; r < 4; ++r) {
                    int row = rt * 16 + q * 4 + r;
                    mn[r] = sm.p1.mstat[hh_l][row][0];
                    rs[r] = sm.p1.mstat[hh_l][row][1];
                }
                int tk1 = hh * 2 + (rt >> 1);
                int rowsel = (rt * 2 + (q >> 1)) & 3;
                int jlo = (q & 1) * 4;
#pragma unroll
                for (int nl = 0; nl < 2; ++nl) {
                    int nt = np * 2 + nl;
                    union { unsigned long long q1; unsigned short u[4]; } pk;
#pragma unroll
                    for (int r = 0; r < 4; ++r)
                        pk.u[r] = f2bf((acc[nl][rt][r] - mn[r]) * rs[r]);
                    long offs = (long)b * 131072 + (long)tk1 * 8192 + nt * 512
                              + (rowsel * 16 + ln) * 8 + jlo;     // in shorts
                    st64(Pf64 + (offs >> 2), pk.q1);
                }
            }
        }
        ++barcnt; bar_b(barp, barcnt * 4, t);   // Pf(b) complete

        // ======== phase 2: agg + shrink/LN/gate + Wout, j-group s16 ========
        float y4[4];
        const int d = t & 255;
        const int rbase = (w >> 2) * 4;
        const int dseg = w & 3;
        {
            const unsigned short* ab = Af + ((long)(b * 4 + s16) * 16) * 512 + lane * 8;
            const unsigned long long* pb = Pf64 + (long)b * 32768 + w * 128 + lane * 2;
            short8 bfr[16];
#pragma unroll
            for (int tk = 0; tk < 16; ++tk) {
                union { unsigned long long q2[2]; short8 v; } u;
                u.q2[0] = ld64(pb + (long)tk * 2048);
                u.q2[1] = ld64(pb + (long)tk * 2048 + 1);
                bfr[tk] = u.v;
            }
            f32x4 acg = (f32x4){0.f, 0.f, 0.f, 0.f};
#pragma unroll
            for (int tk = 0; tk < 16; ++tk) {
                short8 a = *(const short8*)(ab + (long)tk * 512);
                acg = __builtin_amdgcn_mfma_f32_16x16x32_bf16(a, bfr[tk], acg, 0, 0, 0);
            }
            {
                int n = w * 16 + ln;
#pragma unroll
                for (int r = 0; r < 4; ++r) sm.p2.Cs2[q * 4 + r][n] = acg[r];
            }
            __syncthreads();
            float tv[4];
#pragma unroll
            for (int ri = 0; ri < 4; ++ri) {
                int row = b * 64 + j0 + rbase + ri;
                float lin = sm.p2.Cs2[rbase + ri][d];
                float shr = lin - tanhf(lin);
                tv[ri] = projx[row * DD + d] + shr;
            }
#pragma unroll
            for (int ri = 0; ri < 4; ++ri) {
                float sv = tv[ri], sq = tv[ri] * tv[ri];
#pragma unroll
                for (int msk = 32; msk >= 1; msk >>= 1) {
                    sv += __shfl_xor(sv, msk); sq += __shfl_xor(sq, msk);
                }
                if (lane == 0) { sm.p2.part2[rbase + ri][dseg][0] = sv; sm.p2.part2[rbase + ri][dseg][1] = sq; }
            }
            __syncthreads();
#pragma unroll
            for (int ri = 0; ri < 4; ++ri) {
                int r = rbase + ri;
                int row = b * 64 + j0 + r;
                float S  = sm.p2.part2[r][0][0] + sm.p2.part2[r][1][0] + sm.p2.part2[r][2][0] + sm.p2.part2[r][3][0];
                float SS = sm.p2.part2[r][0][1] + sm.p2.part2[r][1][1] + sm.p2.part2[r][2][1] + sm.p2.part2[r][3][1];
                float mn = S * (1.f / 256.f);
                float var = SS * (1.f / 256.f) - mn * mn;
                float rs = rsqrtf(var + 1e-5f);
                float nv = (tv[ri] - mn) * rs;
                float hv = fmaf(shiftb[row * DD + d], nv, scaleb[row * DD + d]);
                sm.p2.hsb[r][d] = f2bf(fmaxf(hv, 0.f));
            }
            __syncthreads();
            f32x4 ac2 = (f32x4){0.f, 0.f, 0.f, 0.f};
#pragma unroll
            for (int tk = 0; tk < 8; ++tk) {
                short8 a = *(const short8*)(&sm.p2.hsb[ln][tk * 32 + q * 8]);
                short8 wf = *(const short8*)(Wof + (long)(w * 8 + tk) * 512 + lane * 8);
                ac2 = __builtin_amdgcn_mfma_f32_16x16x32_bf16(a, wf, ac2, 0, 0, 0);
            }
            __syncthreads();   // hsb reads done before Cs2 overwrite is fine (distinct),
                               // but Cs2 re-write must wait until all tv reads of Cs2 done (they are, pre-part2 sync)
            {
                int n = w * 16 + ln;
#pragma unroll
                for (int r = 0; r < 4; ++r) sm.p2.Cs2[q * 4 + r][n] = ac2[r];
            }
            __syncthreads();
            const float bo_d = bout[d];
            const bool maskz = ((64 - it) > len_s);
#pragma unroll
            for (int ri = 0; ri < 4; ++ri) {
                float y = tanhf(sm.p2.Cs2[rbase + ri][d] + bo_d);
                y4[ri] = maskz ? 0.f : y;
            }
        }

        if (it == 63) {
            // final: out[b,d] += sum_j y[j,d] * root[b,j]  (out pre-zeroed)
            float accf = 0.f;
#pragma unroll
            for (int ri = 0; ri < 4; ++ri)
                accf = fmaf(y4[ri], root[b * 64 + j0 + rbase + ri], accf);
            atomicAdd(out + b * 256 + d, accf);
        } else {
            // export y -> hsb -> h_bf (sc-coherent u64)
            __syncthreads();
#pragma unroll
            for (int ri = 0; ri < 4; ++ri) sm.p2.hsb[rbase + ri][d] = f2bf(y4[ri]);
            __syncthreads();
            if (t < 512) {
                int row = t >> 5, col = (t & 31) * 8;
                union { short8 v; unsigned long long q2[2]; } u;
                u.v = *(const short8*)(&sm.p2.hsb[row][col]);
                unsigned long long* dst = h_bf64 + ((long)(b * 64 + j0 + row) * 256 + col) / 4;
                st64(dst, u.q2[0]);
                st64(dst + 1, u.q2[1]);
            }
            ++barcnt; bar_b(barp, barcnt * 4, t);   // h(b) complete
        }
    }
}

extern "C" void kernel_launch(void* const* d_in, const int* in_sizes, int n_in,
                              void* d_out, int out_size, void* d_ws, size_t ws_size,
                              hipStream_t stream)
{
    const int*   tokens = (const int*)  d_in[0];
    const float* A      = (const float*)d_in[1];
    const float* root   = (const float*)d_in[2];
    const float* emb    = (const float*)d_in[3];
    const float* Wp     = (const float*)d_in[4];
    const float* bp     = (const float*)d_in[5];
    const float* Wi     = (const float*)d_in[6];
    const float* bi     = (const float*)d_in[7];
    const float* Wo     = (const float*)d_in[8];
    const float* bo     = (const float*)d_in[9];
    float* out = (float*)d_out;

    char* ws = (char*)d_ws;
    int*   bars    = (int*)(ws + 0);                            // 4 KB
    float* shiftb  = (float*)(ws + 4096);
    float* scaleb  = shiftb + NROWS * DD;
    float* projx   = scaleb + NROWS * DD;
    unsigned short* h_bf = (unsigned short*)(projx + NROWS * DD);  // 512 KB
    unsigned short* Wf   = h_bf + NROWS * DD;                   // 1 MB
    unsigned short* Pf   = Wf + 524288;                         // 4 MB
    unsigned short* Af   = Pf + 2097152;                        // 1 MB
    unsigned short* Wof  = Af + 524288;                         // 128 KB

    hipMemsetAsync(bars, 0, 4096, stream);
    hipMemsetAsync(h_bf, 0, (size_t)NROWS * DD * sizeof(unsigned short), stream);
    hipMemsetAsync(out, 0, (size_t)out_size * sizeof(float), stream);
    k_cvtW<<<256, 256, 0, stream>>>(Wp, Wf);
    k_cvtA<<<256, 256, 0, stream>>>(A, Af);
    k_cvtWo<<<32, 256, 0, stream>>>(Wo, Wof);
    k_inproj<<<128, 256, 0, stream>>>(tokens, emb, Wi, bi, shiftb, scaleb, projx);
    k_fused<<<64, 1024, 0, stream>>>(tokens, Af, Wf, Wof, bp, bo, projx, shiftb, scaleb,
                                     root, (unsigned long long*)h_bf,
                                     (unsigned long long*)Pf, out, bars);
}

// Round 9
// 2315.749 us; speedup vs baseline: 1.8586x; 1.3737x over previous
//
#include <hip/hip_runtime.h>
#include <hip/hip_bf16.h>

// WeightedGNN forward, MI355X. Round 9: back to multi-launch (coherence free at
// dispatch boundaries) + aggregation folded into the producer: k_projlin computes
// P-chunk in registers, LDS-transposes it, and emits fp32 partial-lin slices.
// Pf (and its 16 MB/iter 4x-amplified remote reads) no longer exists.
// B=16, L=64, D=256, NRELS=8. 64 sequential steps, 2 launches each.

#define DD 256
#define LLEN 64
#define BBAT 16
#define NROWS 1024   // B*L

typedef __attribute__((ext_vector_type(8))) short short8;   // 8 bf16 = 4 VGPRs
typedef __attribute__((ext_vector_type(4))) short short4v;  // 4 bf16 = 8 B
typedef __attribute__((ext_vector_type(4))) float f32x4;

__device__ inline unsigned short f2bf(float x) {
    unsigned int u = __float_as_uint(x);
    unsigned int r = (u + 0x7fffu + ((u >> 16) & 1u)) >> 16;
    return (unsigned short)r;
}

// ---------------- setup: lengths[b] = count(tokens[:,b] != 0) ----------------
__global__ void k_setup(const int* __restrict__ tokens, int* __restrict__ lengths) {
    int b = threadIdx.x;
    if (b < BBAT) {
        int c = 0;
        for (int l = 0; l < LLEN; ++l) c += (tokens[l * BBAT + b] != 0) ? 1 : 0;
        lengths[b] = c;
    }
}

// ------- one-time: W_proj [256][2048] fp32 -> bf16 B-fragment layout ----------
__global__ __launch_bounds__(256) void k_cvtW(const float* __restrict__ Wp,
                                              unsigned short* __restrict__ Wf) {
    int t = blockIdx.x * 256 + threadIdx.x;   // 65536
    int l = t & 63; int rest = t >> 6;
    int tk = rest & 7; rest >>= 3;
    int tn = rest & 15; int hh = rest >> 4;
    int kbase = tk * 32 + (l >> 4) * 8;
    int n = hh * 256 + tn * 16 + (l & 15);
    union { short8 v; unsigned short u[8]; } pk;
#pragma unroll
    for (int j = 0; j < 8; ++j) pk.u[j] = f2bf(Wp[(kbase + j) * 2048 + n]);
    *(short8*)(Wf + (long)t * 8) = pk.v;
}

// ------- one-time: A_rels -> bf16 fragment layout, K-order k = h*64 + i -------
// Af[b][jg(4)][tk(16)][lane(64)][8]: element [m=jg*16+(lane&15)][k=tk*32+(lane>>4)*8+jj].
// Same map serves as A-frag (m=j) or B-frag (n=j) -- MFMA frag algebra is m/n symmetric.
__global__ __launch_bounds__(256) void k_cvtA(const float* __restrict__ A,
                                              unsigned short* __restrict__ Af) {
    int t = blockIdx.x * 256 + threadIdx.x;   // 65536
    int lane = t & 63;
    int tk = (t >> 6) & 15;
    int jg = (t >> 10) & 3;
    int b  = t >> 12;
    int j = jg * 16 + (lane & 15);
    int kbase = tk * 32 + (lane >> 4) * 8;
    int h  = kbase >> 6;
    int i0 = kbase & 63;
    union { short8 v; unsigned short u[8]; } pk;
#pragma unroll
    for (int jj = 0; jj < 8; ++jj)
        pk.u[jj] = f2bf(A[((long)(b * 64 + i0 + jj) * 64 + j) * 8 + h]);
    *(short8*)(Af + (long)t * 8) = pk.v;
}

// ------- one-time: W_out [256][256] fp32 -> bf16 B-fragment layout ------------
__global__ __launch_bounds__(256) void k_cvtWo(const float* __restrict__ Wo,
                                               unsigned short* __restrict__ Wof) {
    int t = blockIdx.x * 256 + threadIdx.x;   // 8192
    int lane = t & 63;
    int tk = (t >> 6) & 7;
    int nt = t >> 9;
    int kbase = tk * 32 + (lane >> 4) * 8;
    int n = nt * 16 + (lane & 15);
    union { short8 v; unsigned short u[8]; } pk;
#pragma unroll
    for (int j = 0; j < 8; ++j) pk.u[j] = f2bf(Wo[(kbase + j) * 256 + n]);
    *(short8*)(Wof + (long)t * 8) = pk.v;
}

// ---------------- in_proj: gather emb + [1024x256]@[256x768] -----------------
__global__ __launch_bounds__(256) void k_inproj(
    const int* __restrict__ tokens, const float* __restrict__ emb,
    const float* __restrict__ W_in, const float* __restrict__ b_in,
    float* __restrict__ shiftb, float* __restrict__ scaleb, float* __restrict__ projx)
{
    __shared__ float xs[8][DD];
    const int t = threadIdx.x;
    const int row0 = blockIdx.x * 8;
    for (int r = 0; r < 8; ++r) {
        int row = row0 + r;
        int b = row >> 6, l = row & 63;
        int tok = tokens[l * BBAT + b];
        xs[r][t] = emb[(long)tok * DD + t];
    }
    __syncthreads();
    float a0[8], a1[8], a2[8];
#pragma unroll
    for (int r = 0; r < 8; ++r) { a0[r] = a1[r] = a2[r] = 0.f; }
    for (int k = 0; k < DD; ++k) {
        float w0 = W_in[k * 768 + t];
        float w1 = W_in[k * 768 + 256 + t];
        float w2 = W_in[k * 768 + 512 + t];
#pragma unroll
        for (int r = 0; r < 8; ++r) {
            float x = xs[r][k];
            a0[r] = fmaf(x, w0, a0[r]);
            a1[r] = fmaf(x, w1, a1[r]);
            a2[r] = fmaf(x, w2, a2[r]);
        }
    }
    float bi0 = b_in[t], bi1 = b_in[256 + t], bi2 = b_in[512 + t];
#pragma unroll
    for (int r = 0; r < 8; ++r) {
        int row = row0 + r;
        shiftb[row * DD + t] = a0[r] + bi0;
        scaleb[row * DD + t] = a1[r] + bi1;
        projx [row * DD + t] = a2[r] + bi2;
    }
}

// ------- per-iter kernel 1: P-chunk = LN(h@Wp+bp) then partial lin -----------
// grid (16 b, 4 s16) x 1024 thr (16 waves). Block handles hh = {2*s16, 2*s16+1}.
// Per hh: GEMM-A (wave w: mt=w&3 i-tile, ng=w>>2 d-group of 4 ntiles; K=256),
// in-fragment LN over d, normalized bf16 -> Pt[256 d][72 pad] LDS (transpose),
// GEMM-lin accumulate (wave w: jt=w&3, dg=w>>2; K=64 per hh from Pt as B-frags,
// Af as A-frags). Output: linp[s16][b][64 j][256 d] fp32 (disjoint slices).
__global__ __launch_bounds__(1024) void k_projlin(
    const unsigned short* __restrict__ h_bf,   // [1024][256] bf16 row-major
    const unsigned short* __restrict__ Wf,     // [8*16][8][64][8]
    const unsigned short* __restrict__ Af,     // [16][4][16][64][8]
    const float* __restrict__ bp,              // [2048]
    float* __restrict__ linp)                  // [4][16][64][256] fp32
{
    __shared__ unsigned short Pt[256][72];     // 36.9 KB, row stride 144 B (16B-mult)
    __shared__ float pstat[64][4][2];
    __shared__ float mstat[64][2];
    const int t = threadIdx.x;
    const int w = t >> 6, lane = t & 63;
    const int q = lane >> 4, ln = lane & 15;
    const int b = blockIdx.x, s16 = blockIdx.y;
    const int mt = w & 3, ng = w >> 2;         // GEMM-A roles
    const int jt = mt,    dg = ng;             // GEMM-lin roles (same split)

    f32x4 acc2[4];
#pragma unroll
    for (int dl = 0; dl < 4; ++dl) acc2[dl] = (f32x4){0.f, 0.f, 0.f, 0.f};

    for (int hl = 0; hl < 2; ++hl) {
        const int hh = s16 * 2 + hl;
        // ---- GEMM-A: P-chunk rows i (mt), cols d (ng*4..+3 ntiles), K=256 ----
        f32x4 accP[4];
#pragma unroll
        for (int nl = 0; nl < 4; ++nl) accP[nl] = (f32x4){0.f, 0.f, 0.f, 0.f};
        const unsigned short* aRow = h_bf + (b * 64 + mt * 16 + ln) * DD + q * 8;
#pragma unroll
        for (int tk = 0; tk < 8; ++tk) {
            short8 a = *(const short8*)(aRow + tk * 32);
#pragma unroll
            for (int nl = 0; nl < 4; ++nl) {
                int nt = ng * 4 + nl;
                short8 bb = *(const short8*)(Wf + ((long)(hh * 16 + nt) * 8 + tk) * 512 + lane * 8);
                accP[nl] = __builtin_amdgcn_mfma_f32_16x16x32_bf16(a, bb, accP[nl], 0, 0, 0);
            }
        }
        // ---- bias + in-fragment LN partials (sum over this wave's 64 d) ----
        float bpv[4];
#pragma unroll
        for (int nl = 0; nl < 4; ++nl) bpv[nl] = bp[hh * 256 + (ng * 4 + nl) * 16 + ln];
        float v[4][4];
#pragma unroll
        for (int r = 0; r < 4; ++r) {
            float s = 0.f, ss = 0.f;
#pragma unroll
            for (int nl = 0; nl < 4; ++nl) {
                float x = accP[nl][r] + bpv[nl];
                v[nl][r] = x;
                s += x; ss += x * x;
            }
#pragma unroll
            for (int msk = 1; msk < 16; msk <<= 1) {
                s += __shfl_xor(s, msk); ss += __shfl_xor(ss, msk);
            }
            if (ln == 0) {
                pstat[mt * 16 + q * 4 + r][ng][0] = s;
                pstat[mt * 16 + q * 4 + r][ng][1] = ss;
            }
        }
        __syncthreads();
        if (t < 64) {
            float S = 0.f, SS = 0.f;
#pragma unroll
            for (int g = 0; g < 4; ++g) { S += pstat[t][g][0]; SS += pstat[t][g][1]; }
            float mean = S * (1.f / 256.f);
            float var  = SS * (1.f / 256.f) - mean * mean;
            mstat[t][0] = mean;
            mstat[t][1] = rsqrtf(var + 1e-5f);
        }
        __syncthreads();
        // ---- normalize -> bf16 -> transpose into Pt[d][i] ----
        float mn[4], rs[4];
#pragma unroll
        for (int r = 0; r < 4; ++r) {
            int irow = mt * 16 + q * 4 + r;
            mn[r] = mstat[irow][0];
            rs[r] = mstat[irow][1];
        }
#pragma unroll
        for (int nl = 0; nl < 4; ++nl) {
            int d = (ng * 4 + nl) * 16 + ln;
            short4v pk;
#pragma unroll
            for (int r = 0; r < 4; ++r)
                pk[r] = (short)f2bf((v[nl][r] - mn[r]) * rs[r]);
            *(short4v*)(&Pt[d][mt * 16 + q * 4]) = pk;
        }
        __syncthreads();
        // ---- GEMM-lin accumulate: out [64 j][256 d], K=64 (this hh) ----
#pragma unroll
        for (int tk2 = 0; tk2 < 2; ++tk2) {
            int gtk = hh * 2 + tk2;
            short8 aA = *(const short8*)(Af + ((long)(b * 4 + jt) * 16 + gtk) * 512 + lane * 8);
#pragma unroll
            for (int dl = 0; dl < 4; ++dl) {
                int dt = dg * 4 + dl;
                short8 bb = *(const short8*)(&Pt[dt * 16 + ln][tk2 * 32 + q * 8]);
                acc2[dl] = __builtin_amdgcn_mfma_f32_16x16x32_bf16(aA, bb, acc2[dl], 0, 0, 0);
            }
        }
        __syncthreads();   // Pt/pstat/mstat reused next hl
    }
    // ---- write partial lin: linp[s16][b][j][d] ----
    float* outp = linp + ((long)(s16 * 16 + b) * 64) * 256;
#pragma unroll
    for (int dl = 0; dl < 4; ++dl) {
        int d = (dg * 4 + dl) * 16 + ln;
#pragma unroll
        for (int r = 0; r < 4; ++r)
            outp[(jt * 16 + q * 4 + r) * 256 + d] = acc2[dl][r];
    }
}

// ------- per-iter kernel 2: sum partials + shrink/LN/gate + Wout + mask -------
// grid (16 b, 4 jg) x 256 thr. R4's verified k_agg epilogue, GEMM1 replaced by
// a 4-way partial sum (64 KB coalesced reads).
__global__ __launch_bounds__(256) void k_gate(
    const float* __restrict__ linp,            // [4][16][64][256]
    const float* __restrict__ projx,
    const float* __restrict__ shiftb,
    const float* __restrict__ scaleb,
    const unsigned short* __restrict__ Wof,    // [16][8][64][8]
    const float* __restrict__ bout,
    const int* __restrict__ lengths,
    float* __restrict__ h_out,                 // [1024][256] fp32 (last iter only)
    unsigned short* __restrict__ h_bf,         // [1024][256] bf16
    int i_val, int write_f32)
{
    __shared__ float Cs[16][260];
    __shared__ unsigned short hsb[16][264];
    __shared__ float part[4][16][2];
    const int t = threadIdx.x;
    const int wv = t >> 6, lane = t & 63;
    const int b = blockIdx.x, jg = blockIdx.y;
    const int j0 = jg * 16;

    // ---- lin = sum of 4 partials ----
    float lp[16];
#pragma unroll
    for (int r = 0; r < 16; ++r) lp[r] = 0.f;
#pragma unroll
    for (int p = 0; p < 4; ++p) {
        const float* src = linp + ((long)(p * 16 + b) * 64 + j0) * 256 + t;
#pragma unroll
        for (int r = 0; r < 16; ++r) lp[r] += src[r * 256];
    }
    // ---- shrink, +projx, LN over d, gate, relu -> hsb (bf16) ----
    float tv[16];
#pragma unroll
    for (int r = 0; r < 16; ++r) {
        int row = b * 64 + j0 + r;
        float shr = lp[r] - tanhf(lp[r]);
        tv[r] = projx[row * DD + t] + shr;
    }
    for (int r = 0; r < 16; ++r) {
        float s = tv[r], ss = tv[r] * tv[r];
#pragma unroll
        for (int m = 32; m >= 1; m >>= 1) { s += __shfl_xor(s, m); ss += __shfl_xor(ss, m); }
        if (lane == 0) { part[wv][r][0] = s; part[wv][r][1] = ss; }
    }
    __syncthreads();
#pragma unroll
    for (int r = 0; r < 16; ++r) {
        int row = b * 64 + j0 + r;
        float s  = part[0][r][0] + part[1][r][0] + part[2][r][0] + part[3][r][0];
        float ss = part[0][r][1] + part[1][r][1] + part[2][r][1] + part[3][r][1];
        float mean = s * (1.f / 256.f);
        float var  = ss * (1.f / 256.f) - mean * mean;
        float rstd = rsqrtf(var + 1e-5f);
        float nv = (tv[r] - mean) * rstd;
        float hv = fmaf(shiftb[row * DD + t], nv, scaleb[row * DD + t]);
        hsb[r][t] = f2bf(fmaxf(hv, 0.f));
    }
    __syncthreads();
    // ---- GEMM2: y = h @ W_out ----
    f32x4 acc2[4];
#pragma unroll
    for (int nt = 0; nt < 4; ++nt) acc2[nt] = (f32x4){0.f, 0.f, 0.f, 0.f};
#pragma unroll
    for (int tk = 0; tk < 8; ++tk) {
        short8 a = *(const short8*)(&hsb[lane & 15][tk * 32 + (lane >> 4) * 8]);
#pragma unroll
        for (int nt = 0; nt < 4; ++nt) {
            short8 wfr = *(const short8*)(Wof + (long)((wv * 4 + nt) * 8 + tk) * 512 + lane * 8);
            acc2[nt] = __builtin_amdgcn_mfma_f32_16x16x32_bf16(a, wfr, acc2[nt], 0, 0, 0);
        }
    }
#pragma unroll
    for (int nt = 0; nt < 4; ++nt) {
        int n = wv * 64 + nt * 16 + (lane & 15);
        int m0 = (lane >> 4) * 4;
#pragma unroll
        for (int r = 0; r < 4; ++r) Cs[m0 + r][n] = acc2[nt][r];
    }
    __syncthreads();
    const float bo_t = bout[t];
    const bool maskz = (i_val > lengths[b]);
#pragma unroll
    for (int r = 0; r < 16; ++r) {
        int row = b * 64 + j0 + r;
        float y = tanhf(Cs[r][t] + bo_t);
        float ym = maskz ? 0.f : y;
        h_bf[row * DD + t] = f2bf(ym);
        if (write_f32) h_out[row * DD + t] = ym;
    }
}

// ---------------- final: out[b,d] = sum_i h[b,i,d] * root[b,i] ----------------
__global__ __launch_bounds__(256) void k_final(
    const float* __restrict__ h_buf, const float* __restrict__ root,
    float* __restrict__ out)
{
    const int t = threadIdx.x;
    const int b = blockIdx.x;
    float acc = 0.f;
    for (int i = 0; i < LLEN; ++i)
        acc = fmaf(h_buf[(b * 64 + i) * DD + t], root[b * 64 + i], acc);
    out[b * DD + t] = acc;
}

extern "C" void kernel_launch(void* const* d_in, const int* in_sizes, int n_in,
                              void* d_out, int out_size, void* d_ws, size_t ws_size,
                              hipStream_t stream)
{
    const int*   tokens = (const int*)  d_in[0];
    const float* A      = (const float*)d_in[1];
    const float* root   = (const float*)d_in[2];
    const float* emb    = (const float*)d_in[3];
    const float* Wp     = (const float*)d_in[4];
    const float* bp     = (const float*)d_in[5];
    const float* Wi     = (const float*)d_in[6];
    const float* bi     = (const float*)d_in[7];
    const float* Wo     = (const float*)d_in[8];
    const float* bo     = (const float*)d_in[9];
    float* out = (float*)d_out;

    char* ws = (char*)d_ws;
    int*   lengths = (int*)(ws + 0);                            // 1 KB
    float* shiftb  = (float*)(ws + 1024);
    float* scaleb  = shiftb + NROWS * DD;
    float* projx   = scaleb + NROWS * DD;
    float* h_out   = projx  + NROWS * DD;                       // 1 MB fp32
    float* linp    = h_out  + NROWS * DD;                       // 4 MB fp32
    unsigned short* h_bf = (unsigned short*)(linp + 4 * NROWS * DD);  // 512 KB
    unsigned short* Wf   = h_bf + NROWS * DD;                   // 1 MB
    unsigned short* Af   = Wf + 524288;                         // 1 MB
    unsigned short* Wof  = Af + 524288;                         // 128 KB

    hipMemsetAsync(h_bf, 0, (size_t)NROWS * DD * sizeof(unsigned short), stream);
    k_setup<<<1, 64, 0, stream>>>(tokens, lengths);
    k_cvtW<<<256, 256, 0, stream>>>(Wp, Wf);
    k_cvtA<<<256, 256, 0, stream>>>(A, Af);
    k_cvtWo<<<32, 256, 0, stream>>>(Wo, Wof);
    k_inproj<<<128, 256, 0, stream>>>(tokens, emb, Wi, bi, shiftb, scaleb, projx);
    for (int it = 0; it < 64; ++it) {
        int i_val = 64 - it;   // i runs L..1
        k_projlin<<<dim3(16, 4), 1024, 0, stream>>>(h_bf, Wf, Af, bp, linp);
        k_gate<<<dim3(16, 4), 256, 0, stream>>>(linp, projx, shiftb, scaleb,
                                                Wof, bo, lengths, h_out, h_bf,
                                                i_val, (it == 63) ? 1 : 0);
    }
    k_final<<<16, 256, 0, stream>>>(h_out, root, out);
}